// Round 1
// baseline (4159.995 us; speedup 1.0000x reference)
//
#include <hip/hip_runtime.h>

typedef _Float16 half_t;
typedef _Float16 half2_t __attribute__((ext_vector_type(2)));
typedef _Float16 half8_t __attribute__((ext_vector_type(8)));
typedef float floatx4 __attribute__((ext_vector_type(4)));
typedef unsigned int u32;

#define EMBED 512
#define HID 512
#define BATCH 32
#define SEQ 1024
#define M_TOT (BATCH * SEQ)          // 32768
#define DSTRIDE ((size_t)1 << 24)    // 32768*512 elems per direction

#ifndef __has_builtin
#define __has_builtin(x) 0
#endif

static __device__ __forceinline__ float fdot2f(half2_t a, half2_t b, float c) {
#if __has_builtin(__builtin_amdgcn_fdot2)
  return __builtin_amdgcn_fdot2(a, b, c, false);
#else
  return c + (float)a[0] * (float)b[0] + (float)a[1] * (float)b[1];
#endif
}

template <int CTRL>
static __device__ __forceinline__ float dpp_add(float x) {
  int xi = __builtin_bit_cast(int, x);
  int yi = __builtin_amdgcn_update_dpp(xi, xi, CTRL, 0xf, 0xf, false);
  return x + __builtin_bit_cast(float, yi);
}

static __device__ __forceinline__ float tanh_fast(float x) {
  float e = __expf(2.0f * x);
  return 1.0f - 2.0f * __builtin_amdgcn_rcpf(e + 1.0f);
}

// ---------------- K0: weight conversion / layout prep ----------------
__global__ __launch_bounds__(256) void k0_prep(
    const float* __restrict__ Wihf, const float* __restrict__ Whhf,
    const float* __restrict__ bihf, const float* __restrict__ bhhf,
    const float* __restrict__ Wihb, const float* __restrict__ Whhb,
    const float* __restrict__ bihb, const float* __restrict__ bhhb,
    half_t* __restrict__ wih16, u32* __restrict__ whh_u,
    float* __restrict__ biassum) {
  const int g = blockIdx.x * 256 + threadIdx.x;  // grid 2048*256 = 524288
  {
    // wih16[n][k], n in [0,1024): fwd rows then bwd rows
    const int n = g >> 9, k = g & 511;
    const float* src = (n < 512) ? Wihf : Wihb;
    wih16[g] = (half_t)src[(size_t)(n & 511) * 512 + k];
  }
  if (g < 262144) {
    // whh_u flat: ((d*32 + p4)*1024 + t)*4 + w4
    const int d = g >> 17;
    const int r = g & 131071;
    const int p4 = r >> 12;
    const int t = (r >> 2) & 1023;
    const int w4 = r & 3;
    const int p = p4 * 4 + w4;       // pair index 0..127
    const int jj = p >> 4, pi = p & 15;
    const int j = ((t >> 4) << 3) + jj;     // output index
    const int i = ((t & 15) << 5) + pi * 2; // input index (even)
    const float* W = d ? Whhb : Whhf;
    half2_t h2 = {(half_t)W[(size_t)j * 512 + i], (half_t)W[(size_t)j * 512 + i + 1]};
    whh_u[g] = __builtin_bit_cast(u32, h2);
  }
  if (g < 1024) {
    biassum[g] = (g < 512) ? (bihf[g] + bhhf[g]) : (bihb[g - 512] + bhhb[g - 512]);
  }
}

// ---------------- K1: input projection (MFMA f16) ----------------
__global__ __launch_bounds__(256) void k1_proj(
    const int* __restrict__ tok, const float* __restrict__ emb,
    const half_t* __restrict__ wih, const float* __restrict__ biassum,
    half_t* __restrict__ x) {
  __shared__ half_t At[64][520];  // 64 rows x 512 + 8 pad (16B) -> 2-way banks max
  const int t = threadIdx.x;
  const int m0 = blockIdx.x * 64;
  {
    const int r = t >> 2;
    const int c0 = (t & 3) << 7;
    const int token = tok[m0 + r];
    const float* er = emb + (size_t)token * EMBED + c0;
#pragma unroll
    for (int cc = 0; cc < 128; cc += 4) {
      floatx4 v = *(const floatx4*)(er + cc);
      At[r][c0 + cc]     = (half_t)v[0];
      At[r][c0 + cc + 1] = (half_t)v[1];
      At[r][c0 + cc + 2] = (half_t)v[2];
      At[r][c0 + cc + 3] = (half_t)v[3];
    }
  }
  __syncthreads();
  const int w = t >> 6, l = t & 63;
  const int lrow = l & 15, lk = (l >> 4) << 3;
#pragma unroll 1
  for (int nb = 0; nb < 1024; nb += 256) {
    const int n0 = nb + w * 64;
    floatx4 acc[4][4] = {};
    for (int k0 = 0; k0 < 512; k0 += 32) {
      half8_t a[4], bf[4];
#pragma unroll
      for (int mi = 0; mi < 4; ++mi)
        a[mi] = *(const half8_t*)&At[mi * 16 + lrow][k0 + lk];
#pragma unroll
      for (int ni = 0; ni < 4; ++ni)
        bf[ni] = *(const half8_t*)(wih + (size_t)(n0 + ni * 16 + lrow) * 512 + k0 + lk);
#pragma unroll
      for (int mi = 0; mi < 4; ++mi)
#pragma unroll
        for (int ni = 0; ni < 4; ++ni)
          acc[mi][ni] = __builtin_amdgcn_mfma_f32_16x16x32_f16(a[mi], bf[ni], acc[mi][ni], 0, 0, 0);
    }
#pragma unroll
    for (int ni = 0; ni < 4; ++ni) {
      const int n = n0 + ni * 16 + lrow;
      const float bias = biassum[n];
      const int dd = n >> 9, hh = n & 511;
#pragma unroll
      for (int mi = 0; mi < 4; ++mi) {
        const int mrow = m0 + mi * 16 + ((l >> 4) << 2);
        half_t* op = x + (size_t)dd * DSTRIDE + (size_t)mrow * HID + hh;
#pragma unroll
        for (int q = 0; q < 4; ++q)
          op[(size_t)q * HID] = (half_t)(acc[mi][ni][q] + bias);
      }
    }
  }
}

// ---------------- K2: persistent RNN scan, 1 WG per (b, dir) ----------------
__global__ __launch_bounds__(1024) void k2_scan(
    const u32* __restrict__ whh_u, half_t* __restrict__ xfeats) {
  const int t = threadIdx.x;
  const int d = blockIdx.x & 1;
  const int b = blockIdx.x >> 1;
  const int jg = t >> 4;    // 64 j-groups of 8 outputs
  const int ir = t & 15;    // 16 i-rows of 32 inputs
  const int swzr = (ir >> 1) & 3;

  __shared__ u32 hls[2][256];  // two 1KB h buffers (512 f16 each, swizzled)
  ((u32*)hls)[t & 511] = 0u;

  // load 256 f16 weights -> 128 uint regs (coalesced: consecutive t -> consecutive uint4)
  u32 w[128];
  const uint4* wp = (const uint4*)whh_u + (size_t)d * 32768 + t;
#pragma unroll
  for (int p4 = 0; p4 < 32; ++p4) {
    uint4 u = wp[(size_t)p4 * 1024];
    w[p4 * 4 + 0] = u.x; w[p4 * 4 + 1] = u.y;
    w[p4 * 4 + 2] = u.z; w[p4 * 4 + 3] = u.w;
  }
#define W2(idx) __builtin_bit_cast(half2_t, w[(idx)])

  const int jmine = (jg << 3) + (ir & 7);
  const int sdir = d ? -1 : 1;
  const int s0 = d ? (SEQ - 1) : 0;
  half_t* xp = xfeats + (size_t)d * DSTRIDE + (size_t)(b * SEQ + s0) * HID + jmine;
  half_t xcur = *xp;
  __syncthreads();

  int cur = 0;
  char* lbase = (char*)hls;
  for (int s = 0; s < SEQ; ++s) {
    half_t xnext = (half_t)0.f;
    if (s < SEQ - 1) xnext = xp[sdir * HID];

    float acc[8] = {0.f, 0.f, 0.f, 0.f, 0.f, 0.f, 0.f, 0.f};
    const char* rb = lbase + cur * 1024 + ir * 64;
#pragma unroll
    for (int c = 0; c < 4; ++c) {
      uint4 hv = *(const uint4*)(rb + ((c ^ swzr) << 4));
      half2_t h0 = __builtin_bit_cast(half2_t, hv.x);
      half2_t h1 = __builtin_bit_cast(half2_t, hv.y);
      half2_t h2 = __builtin_bit_cast(half2_t, hv.z);
      half2_t h3 = __builtin_bit_cast(half2_t, hv.w);
#pragma unroll
      for (int jj = 0; jj < 8; ++jj) {
        float a = acc[jj];
        a = fdot2f(h0, W2(jj * 16 + c * 4 + 0), a);
        a = fdot2f(h1, W2(jj * 16 + c * 4 + 1), a);
        a = fdot2f(h2, W2(jj * 16 + c * 4 + 2), a);
        a = fdot2f(h3, W2(jj * 16 + c * 4 + 3), a);
        acc[jj] = a;
      }
    }
    // reduce across the 16 i-rows (lanes of each aligned 16-lane row) via DPP
#pragma unroll
    for (int jj = 0; jj < 8; ++jj) {
      float a = acc[jj];
      a = dpp_add<0xB1>(a);   // xor 1 (quad_perm [1,0,3,2])
      a = dpp_add<0x4E>(a);   // xor 2 (quad_perm [2,3,0,1])
      a = dpp_add<0x141>(a);  // xor 4 (row_half_mirror; quads uniform)
      a = dpp_add<0x140>(a);  // xor 8 (row_mirror; halves uniform)
      acc[jj] = a;
    }
    // lane (ir&7) selects its own output jj
    float s1a = (ir & 1) ? acc[1] : acc[0];
    float s1b = (ir & 1) ? acc[3] : acc[2];
    float s1c = (ir & 1) ? acc[5] : acc[4];
    float s1d = (ir & 1) ? acc[7] : acc[6];
    float s2a = (ir & 2) ? s1b : s1a;
    float s2b = (ir & 2) ? s1d : s1c;
    float v = (ir & 4) ? s2b : s2a;

    float hvf = tanh_fast(v + (float)xcur);
    half_t hn = (half_t)hvf;
    if (ir < 8) {
      const int wb = ((jg >> 2) << 6) + ((((jg & 3) ^ ((jg >> 3) & 3))) << 4) + (ir << 1);
      *(half_t*)(lbase + (cur ^ 1) * 1024 + wb) = hn;
      *xp = hn;  // feats overwrite consumed x slot
    }
    xcur = xnext;
    xp += sdir * HID;
    __syncthreads();
    cur ^= 1;
  }
#undef W2
}

// ---------------- K3: classifier ----------------
__global__ __launch_bounds__(256) void k3_cls(
    const half_t* __restrict__ feats, const float* __restrict__ wcls,
    const float* __restrict__ bcls, float* __restrict__ out) {
  __shared__ float wl[2048];
  for (int i = threadIdx.x; i < 2048; i += 256) wl[i] = wcls[i];
  __syncthreads();
  const int l = threadIdx.x & 63;
  const int waveg = (blockIdx.x * 256 + threadIdx.x) >> 6;
  const int kb = l << 4;
  const int dd = kb >> 9, hh = kb & 511;
  const float b0 = bcls[0], b1 = bcls[1];
  for (int m = waveg; m < M_TOT; m += 2048) {
    const half_t* fp = feats + (size_t)dd * DSTRIDE + (size_t)m * HID + hh;
    half8_t f0 = *(const half8_t*)fp;
    half8_t f1 = *(const half8_t*)(fp + 8);
    float c0 = 0.f, c1 = 0.f;
#pragma unroll
    for (int j = 0; j < 8; ++j) {
      float fv = (float)f0[j];
      c0 += fv * wl[kb + j];
      c1 += fv * wl[1024 + kb + j];
    }
#pragma unroll
    for (int j = 0; j < 8; ++j) {
      float fv = (float)f1[j];
      c0 += fv * wl[kb + 8 + j];
      c1 += fv * wl[1024 + kb + 8 + j];
    }
#pragma unroll
    for (int off = 1; off < 64; off <<= 1) {
      c0 += __shfl_xor(c0, off, 64);
      c1 += __shfl_xor(c1, off, 64);
    }
    if (l == 0) {
      out[(size_t)m * 2]     = c0 + b0;
      out[(size_t)m * 2 + 1] = c1 + b1;
    }
  }
}

extern "C" void kernel_launch(void* const* d_in, const int* in_sizes, int n_in,
                              void* d_out, int out_size, void* d_ws, size_t ws_size,
                              hipStream_t stream) {
  const int*   tok  = (const int*)d_in[0];
  const float* emb  = (const float*)d_in[1];
  const float* Wihf = (const float*)d_in[2];
  const float* Whhf = (const float*)d_in[3];
  const float* bihf = (const float*)d_in[4];
  const float* bhhf = (const float*)d_in[5];
  const float* Wihb = (const float*)d_in[6];
  const float* Whhb = (const float*)d_in[7];
  const float* bihb = (const float*)d_in[8];
  const float* bhhb = (const float*)d_in[9];
  const float* Wcls = (const float*)d_in[10];
  const float* bcls = (const float*)d_in[11];
  float* out = (float*)d_out;

  char* ws = (char*)d_ws;
  u32*    whh_u   = (u32*)ws;                    // 1 MB
  half_t* wih16   = (half_t*)(ws + (1 << 20));   // 1 MB
  float*  biassum = (float*)(ws + (2 << 20));    // 4 KB
  half_t* xfeats  = (half_t*)(ws + (4 << 20));   // 64 MB (x, overwritten by feats)

  hipLaunchKernelGGL(k0_prep, dim3(2048), dim3(256), 0, stream,
                     Wihf, Whhf, bihf, bhhf, Wihb, Whhb, bihb, bhhb,
                     wih16, whh_u, biassum);
  hipLaunchKernelGGL(k1_proj, dim3(512), dim3(256), 0, stream,
                     tok, emb, wih16, biassum, xfeats);
  hipLaunchKernelGGL(k2_scan, dim3(64), dim3(1024), 0, stream, whh_u, xfeats);
  hipLaunchKernelGGL(k3_cls, dim3(512), dim3(256), 0, stream,
                     xfeats, Wcls, bcls, out);
}

// Round 4
// 1702.050 us; speedup vs baseline: 2.4441x; 2.4441x over previous
//
#include <hip/hip_runtime.h>

typedef _Float16 half_t;
typedef _Float16 half2_t __attribute__((ext_vector_type(2)));
typedef _Float16 half8_t __attribute__((ext_vector_type(8)));
typedef float floatx4 __attribute__((ext_vector_type(4)));
typedef unsigned int u32;

#define EMBED 512
#define HID 512
#define BATCH 32
#define SEQ 1024
#define M_TOT (BATCH * SEQ)          // 32768
#define DSTRIDE ((size_t)1 << 24)    // 32768*512 elems per direction

#ifndef __has_builtin
#define __has_builtin(x) 0
#endif

static __device__ __forceinline__ float fdot2f(half2_t a, half2_t b, float c) {
#if __has_builtin(__builtin_amdgcn_fdot2)
  return __builtin_amdgcn_fdot2(a, b, c, false);
#else
  return c + (float)a[0] * (float)b[0] + (float)a[1] * (float)b[1];
#endif
}

template <int CTRL>
static __device__ __forceinline__ float dpp_add(float x) {
  int xi = __builtin_bit_cast(int, x);
  int yi = __builtin_amdgcn_update_dpp(xi, xi, CTRL, 0xf, 0xf, false);
  return x + __builtin_bit_cast(float, yi);
}

static __device__ __forceinline__ float tanh_fast(float x) {
  float e = __expf(2.0f * x);
  return 1.0f - 2.0f * __builtin_amdgcn_rcpf(e + 1.0f);
}

// ---------------- K0: weight conversion / layout prep ----------------
// whh_all flat u32 index: (((d*8 + c)*8 + jj)*512 + t)*4 + pp
//   thread t of k2 owns outputs j = (t>>3)*8 + jj, input-pairs p = (t&7)*32 + c*4 + pp
__global__ __launch_bounds__(256) void k0_prep(
    const float* __restrict__ Wihf, const float* __restrict__ Whhf,
    const float* __restrict__ bihf, const float* __restrict__ bhhf,
    const float* __restrict__ Wihb, const float* __restrict__ Whhb,
    const float* __restrict__ bihb, const float* __restrict__ bhhb,
    half_t* __restrict__ wih16, u32* __restrict__ whh_all,
    float* __restrict__ biassum) {
  const int g = blockIdx.x * 256 + threadIdx.x;  // grid 2048*256 = 524288
  {
    // wih16[n][k], n in [0,1024): fwd rows then bwd rows
    const int n = g >> 9, k = g & 511;
    const float* src = (n < 512) ? Wihf : Wihb;
    wih16[g] = (half_t)src[(size_t)(n & 511) * 512 + k];
  }
  if (g < 262144) {
    const int pp = g & 3;
    const int tt = (g >> 2) & 511;
    const int jj = (g >> 11) & 7;
    const int c  = (g >> 14) & 7;
    const int dd = g >> 17;
    const int j = ((tt >> 3) << 3) + jj;
    const int p = ((tt & 7) << 5) + (c << 2) + pp;
    const int i = p << 1;
    const float* W = dd ? Whhb : Whhf;
    half2_t h2 = {(half_t)W[(size_t)j * 512 + i], (half_t)W[(size_t)j * 512 + i + 1]};
    whh_all[g] = __builtin_bit_cast(u32, h2);
  }
  if (g < 1024) {
    biassum[g] = (g < 512) ? (bihf[g] + bhhf[g]) : (bihb[g - 512] + bhhb[g - 512]);
  }
}

// ---------------- K1: input projection (MFMA f16) ----------------
__global__ __launch_bounds__(256) void k1_proj(
    const int* __restrict__ tok, const float* __restrict__ emb,
    const half_t* __restrict__ wih, const float* __restrict__ biassum,
    half_t* __restrict__ x) {
  __shared__ half_t At[64][520];
  const int t = threadIdx.x;
  const int m0 = blockIdx.x * 64;
  {
    const int r = t >> 2;
    const int c0 = (t & 3) << 7;
    const int token = tok[m0 + r];
    const float* er = emb + (size_t)token * EMBED + c0;
#pragma unroll
    for (int cc = 0; cc < 128; cc += 4) {
      floatx4 v = *(const floatx4*)(er + cc);
      At[r][c0 + cc]     = (half_t)v[0];
      At[r][c0 + cc + 1] = (half_t)v[1];
      At[r][c0 + cc + 2] = (half_t)v[2];
      At[r][c0 + cc + 3] = (half_t)v[3];
    }
  }
  __syncthreads();
  const int w = t >> 6, l = t & 63;
  const int lrow = l & 15, lk = (l >> 4) << 3;
#pragma unroll 1
  for (int nb = 0; nb < 1024; nb += 256) {
    const int n0 = nb + w * 64;
    floatx4 acc[4][4] = {};
    for (int k0 = 0; k0 < 512; k0 += 32) {
      half8_t a[4], bf[4];
#pragma unroll
      for (int mi = 0; mi < 4; ++mi)
        a[mi] = *(const half8_t*)&At[mi * 16 + lrow][k0 + lk];
#pragma unroll
      for (int ni = 0; ni < 4; ++ni)
        bf[ni] = *(const half8_t*)(wih + (size_t)(n0 + ni * 16 + lrow) * 512 + k0 + lk);
#pragma unroll
      for (int mi = 0; mi < 4; ++mi)
#pragma unroll
        for (int ni = 0; ni < 4; ++ni)
          acc[mi][ni] = __builtin_amdgcn_mfma_f32_16x16x32_f16(a[mi], bf[ni], acc[mi][ni], 0, 0, 0);
    }
#pragma unroll
    for (int ni = 0; ni < 4; ++ni) {
      const int n = n0 + ni * 16 + lrow;
      const float bias = biassum[n];
      const int dd = n >> 9, hh = n & 511;
#pragma unroll
      for (int mi = 0; mi < 4; ++mi) {
        const int mrow = m0 + mi * 16 + ((l >> 4) << 2);
        half_t* op = x + (size_t)dd * DSTRIDE + (size_t)mrow * HID + hh;
#pragma unroll
        for (int q = 0; q < 4; ++q)
          op[(size_t)q * HID] = (half_t)(acc[mi][ni][q] + bias);
      }
    }
  }
}

// ---------------- K2: persistent RNN scan, 1 WG (512 thr) per (b, dir) ----------------
// thread t: outputs j in [ (t>>3)*8, +8 ), inputs i in [ (t&7)*64, +64 )
// weights: chunks c=0..5 in VGPRs (192 u32), c=6..7 in LDS (64 u32)
__global__ __launch_bounds__(512, 2) void k2_scan(
    const u32* __restrict__ whh, half_t* __restrict__ xfeats) {
  __shared__ uint4 wlds[16][512];   // 128 KB
  __shared__ u32 hbuf[2][256];      // 2 x 1KB h buffers (512 f16, XOR-chunk swizzled)
  const int t = threadIdx.x;
  const int d = blockIdx.x & 1;
  const int b = blockIdx.x >> 1;
  const int ir = t & 7;

  const uint4* wg = (const uint4*)whh + (size_t)d * 32768 + t;
  u32 wr[192];
#pragma unroll
  for (int c = 0; c < 6; ++c)
#pragma unroll
    for (int jj = 0; jj < 8; ++jj) {
      uint4 u = wg[(size_t)(c * 8 + jj) * 512];
      const int base = (c * 8 + jj) * 4;
      wr[base + 0] = u.x; wr[base + 1] = u.y;
      wr[base + 2] = u.z; wr[base + 3] = u.w;
    }
#pragma unroll
  for (int k = 0; k < 16; ++k)
    wlds[k][t] = wg[(size_t)(48 + k) * 512];
  if (t < 256) hbuf[0][t] = 0u;
#define W2(idx) __builtin_bit_cast(half2_t, wr[(idx)])

  const int sdir = d ? -1 : 1;
  const int s0 = d ? (SEQ - 1) : 0;
  half_t* xp = xfeats + (size_t)d * DSTRIDE + (size_t)(b * SEQ + s0) * HID + t;
  half_t xcur = *xp;
  __syncthreads();

  int cur = 0;
  for (int s = 0; s < SEQ; ++s) {
    half_t xnext = (half_t)0.f;
    if (s < SEQ - 1) xnext = xp[sdir * HID];

    float acc[8] = {0.f, 0.f, 0.f, 0.f, 0.f, 0.f, 0.f, 0.f};
    const u32* hb = hbuf[cur];
#pragma unroll
    for (int c = 0; c < 8; ++c) {
      uint4 hv = *(const uint4*)(hb + (ir << 5) + (((c ^ ir) & 7) << 2));
      half2_t h0 = __builtin_bit_cast(half2_t, hv.x);
      half2_t h1 = __builtin_bit_cast(half2_t, hv.y);
      half2_t h2 = __builtin_bit_cast(half2_t, hv.z);
      half2_t h3 = __builtin_bit_cast(half2_t, hv.w);
#pragma unroll
      for (int jj = 0; jj < 8; ++jj) {
        half2_t w0, w1, w2, w3;
        if (c < 6) {
          const int base = (c * 8 + jj) * 4;
          w0 = W2(base + 0); w1 = W2(base + 1);
          w2 = W2(base + 2); w3 = W2(base + 3);
        } else {
          uint4 wv = wlds[(c - 6) * 8 + jj][t];
          w0 = __builtin_bit_cast(half2_t, wv.x);
          w1 = __builtin_bit_cast(half2_t, wv.y);
          w2 = __builtin_bit_cast(half2_t, wv.z);
          w3 = __builtin_bit_cast(half2_t, wv.w);
        }
        float a = acc[jj];
        a = fdot2f(h0, w0, a);
        a = fdot2f(h1, w1, a);
        a = fdot2f(h2, w2, a);
        a = fdot2f(h3, w3, a);
        acc[jj] = a;
      }
    }
    // reduce across the 8 i-rows (8 consecutive lanes) via DPP
#pragma unroll
    for (int jj = 0; jj < 8; ++jj) {
      float a = acc[jj];
      a = dpp_add<0xB1>(a);   // xor 1 (quad_perm [1,0,3,2])
      a = dpp_add<0x4E>(a);   // xor 2 (quad_perm [2,3,0,1])
      a = dpp_add<0x141>(a);  // xor 4 (row_half_mirror; quads uniform)
      acc[jj] = a;
    }
    // lane ir selects its own output jj = ir
    float s1a = (ir & 1) ? acc[1] : acc[0];
    float s1b = (ir & 1) ? acc[3] : acc[2];
    float s1c = (ir & 1) ? acc[5] : acc[4];
    float s1d = (ir & 1) ? acc[7] : acc[6];
    float s2a = (ir & 2) ? s1b : s1a;
    float s2b = (ir & 2) ? s1d : s1c;
    float v = (ir & 4) ? s2b : s2a;

    float hvf = tanh_fast(v + (float)xcur);
    half_t hn = (half_t)hvf;
    // write h[j=t] swizzled into next buffer + overwrite consumed x slot
    {
      const int r = t >> 6, cc = (t >> 3) & 7, q = (t >> 1) & 3;
      const int dw = (r << 5) + (((cc ^ r) & 7) << 2) + q;
      *((half_t*)&hbuf[cur ^ 1][dw] + (t & 1)) = hn;
      *xp = hn;
    }
    xcur = xnext;
    xp += sdir * HID;
    __syncthreads();
    cur ^= 1;
  }
#undef W2
}

// ---------------- K3: classifier ----------------
__global__ __launch_bounds__(256) void k3_cls(
    const half_t* __restrict__ feats, const float* __restrict__ wcls,
    const float* __restrict__ bcls, float* __restrict__ out) {
  __shared__ float wl[2048];
  for (int i = threadIdx.x; i < 2048; i += 256) wl[i] = wcls[i];
  __syncthreads();
  const int l = threadIdx.x & 63;
  const int waveg = (blockIdx.x * 256 + threadIdx.x) >> 6;
  const int kb = l << 4;
  const int dd = kb >> 9, hh = kb & 511;
  const float b0 = bcls[0], b1 = bcls[1];
  for (int m = waveg; m < M_TOT; m += 2048) {
    const half_t* fp = feats + (size_t)dd * DSTRIDE + (size_t)m * HID + hh;
    half8_t f0 = *(const half8_t*)fp;
    half8_t f1 = *(const half8_t*)(fp + 8);
    float c0 = 0.f, c1 = 0.f;
#pragma unroll
    for (int j = 0; j < 8; ++j) {
      float fv = (float)f0[j];
      c0 += fv * wl[kb + j];
      c1 += fv * wl[1024 + kb + j];
    }
#pragma unroll
    for (int j = 0; j < 8; ++j) {
      float fv = (float)f1[j];
      c0 += fv * wl[kb + 8 + j];
      c1 += fv * wl[1024 + kb + 8 + j];
    }
#pragma unroll
    for (int off = 1; off < 64; off <<= 1) {
      c0 += __shfl_xor(c0, off, 64);
      c1 += __shfl_xor(c1, off, 64);
    }
    if (l == 0) {
      out[(size_t)m * 2]     = c0 + b0;
      out[(size_t)m * 2 + 1] = c1 + b1;
    }
  }
}

extern "C" void kernel_launch(void* const* d_in, const int* in_sizes, int n_in,
                              void* d_out, int out_size, void* d_ws, size_t ws_size,
                              hipStream_t stream) {
  const int*   tok  = (const int*)d_in[0];
  const float* emb  = (const float*)d_in[1];
  const float* Wihf = (const float*)d_in[2];
  const float* Whhf = (const float*)d_in[3];
  const float* bihf = (const float*)d_in[4];
  const float* bhhf = (const float*)d_in[5];
  const float* Wihb = (const float*)d_in[6];
  const float* Whhb = (const float*)d_in[7];
  const float* bihb = (const float*)d_in[8];
  const float* bhhb = (const float*)d_in[9];
  const float* Wcls = (const float*)d_in[10];
  const float* bcls = (const float*)d_in[11];
  float* out = (float*)d_out;

  char* ws = (char*)d_ws;
  u32*    whh_all = (u32*)ws;                    // 1 MB
  half_t* wih16   = (half_t*)(ws + (1 << 20));   // 1 MB
  float*  biassum = (float*)(ws + (2 << 20));    // 4 KB
  half_t* xfeats  = (half_t*)(ws + (4 << 20));   // 64 MB (x, overwritten by feats)

  hipLaunchKernelGGL(k0_prep, dim3(2048), dim3(256), 0, stream,
                     Wihf, Whhf, bihf, bhhf, Wihb, Whhb, bihb, bhhb,
                     wih16, whh_all, biassum);
  hipLaunchKernelGGL(k1_proj, dim3(512), dim3(256), 0, stream,
                     tok, emb, wih16, biassum, xfeats);
  hipLaunchKernelGGL(k2_scan, dim3(64), dim3(512), 0, stream, whh_all, xfeats);
  hipLaunchKernelGGL(k3_cls, dim3(512), dim3(256), 0, stream,
                     xfeats, Wcls, bcls, out);
}

// Round 5
// 1696.462 us; speedup vs baseline: 2.4522x; 1.0033x over previous
//
#include <hip/hip_runtime.h>

typedef _Float16 half_t;
typedef _Float16 half2_t __attribute__((ext_vector_type(2)));
typedef _Float16 half8_t __attribute__((ext_vector_type(8)));
typedef float floatx4 __attribute__((ext_vector_type(4)));
typedef unsigned int u32;

#define EMBED 512
#define HID 512
#define BATCH 32
#define SEQ 1024
#define M_TOT (BATCH * SEQ)          // 32768
#define DSTRIDE ((size_t)1 << 24)    // 32768*512 elems per direction

#ifndef __has_builtin
#define __has_builtin(x) 0
#endif

static __device__ __forceinline__ float fdot2f(half2_t a, half2_t b, float c) {
#if __has_builtin(__builtin_amdgcn_fdot2)
  return __builtin_amdgcn_fdot2(a, b, c, false);
#else
  return c + (float)a[0] * (float)b[0] + (float)a[1] * (float)b[1];
#endif
}

template <int CTRL>
static __device__ __forceinline__ float dpp_add(float x) {
  int xi = __builtin_bit_cast(int, x);
  int yi = __builtin_amdgcn_update_dpp(xi, xi, CTRL, 0xf, 0xf, false);
  return x + __builtin_bit_cast(float, yi);
}

static __device__ __forceinline__ float tanh_fast(float x) {
  float e = __expf(2.0f * x);
  return 1.0f - 2.0f * __builtin_amdgcn_rcpf(e + 1.0f);
}

// ---------------- K0: weight conversion / layout prep ----------------
// whh_all flat u32 index: (((d*8 + c)*8 + jj)*512 + t)*4 + pp
//   thread t of k2 owns outputs j = (t>>3)*8 + jj, input-pairs p = (t&7)*32 + c*4 + pp
__global__ __launch_bounds__(256) void k0_prep(
    const float* __restrict__ Wihf, const float* __restrict__ Whhf,
    const float* __restrict__ bihf, const float* __restrict__ bhhf,
    const float* __restrict__ Wihb, const float* __restrict__ Whhb,
    const float* __restrict__ bihb, const float* __restrict__ bhhb,
    half_t* __restrict__ wih16, u32* __restrict__ whh_all,
    float* __restrict__ biassum) {
  const int g = blockIdx.x * 256 + threadIdx.x;  // grid 2048*256 = 524288
  {
    // wih16[n][k], n in [0,1024): fwd rows then bwd rows
    const int n = g >> 9, k = g & 511;
    const float* src = (n < 512) ? Wihf : Wihb;
    wih16[g] = (half_t)src[(size_t)(n & 511) * 512 + k];
  }
  if (g < 262144) {
    const int pp = g & 3;
    const int tt = (g >> 2) & 511;
    const int jj = (g >> 11) & 7;
    const int c  = (g >> 14) & 7;
    const int dd = g >> 17;
    const int j = ((tt >> 3) << 3) + jj;
    const int p = ((tt & 7) << 5) + (c << 2) + pp;
    const int i = p << 1;
    const float* W = dd ? Whhb : Whhf;
    half2_t h2 = {(half_t)W[(size_t)j * 512 + i], (half_t)W[(size_t)j * 512 + i + 1]};
    whh_all[g] = __builtin_bit_cast(u32, h2);
  }
  if (g < 1024) {
    biassum[g] = (g < 512) ? (bihf[g] + bhhf[g]) : (bihb[g - 512] + bhhb[g - 512]);
  }
}

// ---------------- K1: input projection (MFMA f16) ----------------
__global__ __launch_bounds__(256) void k1_proj(
    const int* __restrict__ tok, const float* __restrict__ emb,
    const half_t* __restrict__ wih, const float* __restrict__ biassum,
    half_t* __restrict__ x) {
  __shared__ half_t At[64][520];
  const int t = threadIdx.x;
  const int m0 = blockIdx.x * 64;
  {
    const int r = t >> 2;
    const int c0 = (t & 3) << 7;
    const int token = tok[m0 + r];
    const float* er = emb + (size_t)token * EMBED + c0;
#pragma unroll
    for (int cc = 0; cc < 128; cc += 4) {
      floatx4 v = *(const floatx4*)(er + cc);
      At[r][c0 + cc]     = (half_t)v[0];
      At[r][c0 + cc + 1] = (half_t)v[1];
      At[r][c0 + cc + 2] = (half_t)v[2];
      At[r][c0 + cc + 3] = (half_t)v[3];
    }
  }
  __syncthreads();
  const int w = t >> 6, l = t & 63;
  const int lrow = l & 15, lk = (l >> 4) << 3;
#pragma unroll 1
  for (int nb = 0; nb < 1024; nb += 256) {
    const int n0 = nb + w * 64;
    floatx4 acc[4][4] = {};
    for (int k0 = 0; k0 < 512; k0 += 32) {
      half8_t a[4], bf[4];
#pragma unroll
      for (int mi = 0; mi < 4; ++mi)
        a[mi] = *(const half8_t*)&At[mi * 16 + lrow][k0 + lk];
#pragma unroll
      for (int ni = 0; ni < 4; ++ni)
        bf[ni] = *(const half8_t*)(wih + (size_t)(n0 + ni * 16 + lrow) * 512 + k0 + lk);
#pragma unroll
      for (int mi = 0; mi < 4; ++mi)
#pragma unroll
        for (int ni = 0; ni < 4; ++ni)
          acc[mi][ni] = __builtin_amdgcn_mfma_f32_16x16x32_f16(a[mi], bf[ni], acc[mi][ni], 0, 0, 0);
    }
#pragma unroll
    for (int ni = 0; ni < 4; ++ni) {
      const int n = n0 + ni * 16 + lrow;
      const float bias = biassum[n];
      const int dd = n >> 9, hh = n & 511;
#pragma unroll
      for (int mi = 0; mi < 4; ++mi) {
        const int mrow = m0 + mi * 16 + ((l >> 4) << 2);
        half_t* op = x + (size_t)dd * DSTRIDE + (size_t)mrow * HID + hh;
#pragma unroll
        for (int q = 0; q < 4; ++q)
          op[(size_t)q * HID] = (half_t)(acc[mi][ni][q] + bias);
      }
    }
  }
}

// ---------------- K2: persistent RNN scan, 1 WG (512 thr) per (b, dir) ----------------
// thread t: outputs j in [ (t>>3)*8, +8 ), inputs i in [ (t&7)*64, +64 )
// weights: chunks c=0..5 in VGPRs (192 u32), c=6..7 in LDS (64 u32)
// amdgpu_waves_per_eu(2,2): LDS (130KB) already limits to 1 WG/CU = 2 waves/EU;
// pin the allocator's occupancy target so it uses the full 256-VGPR budget
// instead of capping at 128 and spilling wr[192] to scratch.
__global__ __launch_bounds__(512)
__attribute__((amdgpu_waves_per_eu(2, 2)))
void k2_scan(
    const u32* __restrict__ whh, half_t* __restrict__ xfeats) {
  __shared__ uint4 wlds[16][512];   // 128 KB
  __shared__ u32 hbuf[2][256];      // 2 x 1KB h buffers (512 f16, XOR-chunk swizzled)
  const int t = threadIdx.x;
  const int d = blockIdx.x & 1;
  const int b = blockIdx.x >> 1;
  const int ir = t & 7;

  const uint4* wg = (const uint4*)whh + (size_t)d * 32768 + t;
  u32 wr[192];
#pragma unroll
  for (int c = 0; c < 6; ++c)
#pragma unroll
    for (int jj = 0; jj < 8; ++jj) {
      uint4 u = wg[(size_t)(c * 8 + jj) * 512];
      const int base = (c * 8 + jj) * 4;
      wr[base + 0] = u.x; wr[base + 1] = u.y;
      wr[base + 2] = u.z; wr[base + 3] = u.w;
    }
#pragma unroll
  for (int k = 0; k < 16; ++k)
    wlds[k][t] = wg[(size_t)(48 + k) * 512];
  if (t < 256) hbuf[0][t] = 0u;
#define W2(idx) __builtin_bit_cast(half2_t, wr[(idx)])

  const int sdir = d ? -1 : 1;
  const int s0 = d ? (SEQ - 1) : 0;
  half_t* xp = xfeats + (size_t)d * DSTRIDE + (size_t)(b * SEQ + s0) * HID + t;
  half_t xcur = *xp;
  __syncthreads();

  int cur = 0;
  for (int s = 0; s < SEQ; ++s) {
    half_t xnext = (half_t)0.f;
    if (s < SEQ - 1) xnext = xp[sdir * HID];

    float acc[8] = {0.f, 0.f, 0.f, 0.f, 0.f, 0.f, 0.f, 0.f};
    const u32* hb = hbuf[cur];
#pragma unroll
    for (int c = 0; c < 8; ++c) {
      uint4 hv = *(const uint4*)(hb + (ir << 5) + (((c ^ ir) & 7) << 2));
      half2_t h0 = __builtin_bit_cast(half2_t, hv.x);
      half2_t h1 = __builtin_bit_cast(half2_t, hv.y);
      half2_t h2 = __builtin_bit_cast(half2_t, hv.z);
      half2_t h3 = __builtin_bit_cast(half2_t, hv.w);
#pragma unroll
      for (int jj = 0; jj < 8; ++jj) {
        half2_t w0, w1, w2, w3;
        if (c < 6) {
          const int base = (c * 8 + jj) * 4;
          w0 = W2(base + 0); w1 = W2(base + 1);
          w2 = W2(base + 2); w3 = W2(base + 3);
        } else {
          uint4 wv = wlds[(c - 6) * 8 + jj][t];
          w0 = __builtin_bit_cast(half2_t, wv.x);
          w1 = __builtin_bit_cast(half2_t, wv.y);
          w2 = __builtin_bit_cast(half2_t, wv.z);
          w3 = __builtin_bit_cast(half2_t, wv.w);
        }
        float a = acc[jj];
        a = fdot2f(h0, w0, a);
        a = fdot2f(h1, w1, a);
        a = fdot2f(h2, w2, a);
        a = fdot2f(h3, w3, a);
        acc[jj] = a;
      }
    }
    // reduce across the 8 i-rows (8 consecutive lanes) via DPP
#pragma unroll
    for (int jj = 0; jj < 8; ++jj) {
      float a = acc[jj];
      a = dpp_add<0xB1>(a);   // xor 1 (quad_perm [1,0,3,2])
      a = dpp_add<0x4E>(a);   // xor 2 (quad_perm [2,3,0,1])
      a = dpp_add<0x141>(a);  // xor 4 (row_half_mirror; quads uniform)
      acc[jj] = a;
    }
    // lane ir selects its own output jj = ir
    float s1a = (ir & 1) ? acc[1] : acc[0];
    float s1b = (ir & 1) ? acc[3] : acc[2];
    float s1c = (ir & 1) ? acc[5] : acc[4];
    float s1d = (ir & 1) ? acc[7] : acc[6];
    float s2a = (ir & 2) ? s1b : s1a;
    float s2b = (ir & 2) ? s1d : s1c;
    float v = (ir & 4) ? s2b : s2a;

    float hvf = tanh_fast(v + (float)xcur);
    half_t hn = (half_t)hvf;
    // write h[j=t] swizzled into next buffer + overwrite consumed x slot
    {
      const int r = t >> 6, cc = (t >> 3) & 7, q = (t >> 1) & 3;
      const int dw = (r << 5) + (((cc ^ r) & 7) << 2) + q;
      *((half_t*)&hbuf[cur ^ 1][dw] + (t & 1)) = hn;
      *xp = hn;
    }
    xcur = xnext;
    xp += sdir * HID;
    __syncthreads();
    cur ^= 1;
  }
#undef W2
}

// ---------------- K3: classifier ----------------
__global__ __launch_bounds__(256) void k3_cls(
    const half_t* __restrict__ feats, const float* __restrict__ wcls,
    const float* __restrict__ bcls, float* __restrict__ out) {
  __shared__ float wl[2048];
  for (int i = threadIdx.x; i < 2048; i += 256) wl[i] = wcls[i];
  __syncthreads();
  const int l = threadIdx.x & 63;
  const int waveg = (blockIdx.x * 256 + threadIdx.x) >> 6;
  const int kb = l << 4;
  const int dd = kb >> 9, hh = kb & 511;
  const float b0 = bcls[0], b1 = bcls[1];
  for (int m = waveg; m < M_TOT; m += 2048) {
    const half_t* fp = feats + (size_t)dd * DSTRIDE + (size_t)m * HID + hh;
    half8_t f0 = *(const half8_t*)fp;
    half8_t f1 = *(const half8_t*)(fp + 8);
    float c0 = 0.f, c1 = 0.f;
#pragma unroll
    for (int j = 0; j < 8; ++j) {
      float fv = (float)f0[j];
      c0 += fv * wl[kb + j];
      c1 += fv * wl[1024 + kb + j];
    }
#pragma unroll
    for (int j = 0; j < 8; ++j) {
      float fv = (float)f1[j];
      c0 += fv * wl[kb + 8 + j];
      c1 += fv * wl[1024 + kb + 8 + j];
    }
#pragma unroll
    for (int off = 1; off < 64; off <<= 1) {
      c0 += __shfl_xor(c0, off, 64);
      c1 += __shfl_xor(c1, off, 64);
    }
    if (l == 0) {
      out[(size_t)m * 2]     = c0 + b0;
      out[(size_t)m * 2 + 1] = c1 + b1;
    }
  }
}

extern "C" void kernel_launch(void* const* d_in, const int* in_sizes, int n_in,
                              void* d_out, int out_size, void* d_ws, size_t ws_size,
                              hipStream_t stream) {
  const int*   tok  = (const int*)d_in[0];
  const float* emb  = (const float*)d_in[1];
  const float* Wihf = (const float*)d_in[2];
  const float* Whhf = (const float*)d_in[3];
  const float* bihf = (const float*)d_in[4];
  const float* bhhf = (const float*)d_in[5];
  const float* Wihb = (const float*)d_in[6];
  const float* Whhb = (const float*)d_in[7];
  const float* bihb = (const float*)d_in[8];
  const float* bhhb = (const float*)d_in[9];
  const float* Wcls = (const float*)d_in[10];
  const float* bcls = (const float*)d_in[11];
  float* out = (float*)d_out;

  char* ws = (char*)d_ws;
  u32*    whh_all = (u32*)ws;                    // 1 MB
  half_t* wih16   = (half_t*)(ws + (1 << 20));   // 1 MB
  float*  biassum = (float*)(ws + (2 << 20));    // 4 KB
  half_t* xfeats  = (half_t*)(ws + (4 << 20));   // 64 MB (x, overwritten by feats)

  hipLaunchKernelGGL(k0_prep, dim3(2048), dim3(256), 0, stream,
                     Wihf, Whhf, bihf, bhhf, Wihb, Whhb, bihb, bhhb,
                     wih16, whh_all, biassum);
  hipLaunchKernelGGL(k1_proj, dim3(512), dim3(256), 0, stream,
                     tok, emb, wih16, biassum, xfeats);
  hipLaunchKernelGGL(k2_scan, dim3(64), dim3(512), 0, stream, whh_all, xfeats);
  hipLaunchKernelGGL(k3_cls, dim3(512), dim3(256), 0, stream,
                     xfeats, Wcls, bcls, out);
}